// Round 1
// baseline (250.399 us; speedup 1.0000x reference)
//
#include <hip/hip_runtime.h>

// ---------------------------------------------------------------------------
// CausalSelfAttention (B=1, T=2048, DIM=1024, H=8, hd=128, scale=0.12)
// Pipeline: cast->GEMM(qkv,bf16 MFMA)->rmsnorm+rope(q,k)->v-combine+transpose
//           ->flash attention (bf16 MFMA, online softmax)->GEMM(proj)->f32 out
// MFMA layouts (verified per guide m89/m91/m120):
//   A[m=lane&15][k=quad*8+j], B[k=quad*8+j][n=lane&15],
//   C/D: row=quad*4+reg, col=lane&15   (quad = lane>>4)
// ---------------------------------------------------------------------------

typedef __attribute__((ext_vector_type(8))) short short8;      // 8 bf16 (4 VGPR)
typedef __attribute__((ext_vector_type(4))) float fx4;         // MFMA acc
typedef __attribute__((ext_vector_type(8))) unsigned short ushort8;
typedef __attribute__((ext_vector_type(4))) unsigned short ushort4v;
typedef __attribute__((ext_vector_type(2))) unsigned short ushort2v;
typedef __attribute__((ext_vector_type(4))) float float4v;

#define T_SEQ 2048
#define NH 8
#define HD 128

__device__ __forceinline__ unsigned short f2bf(float f) {
  union { float f; unsigned u; } v; v.f = f;
  unsigned u = v.u;
  u += 0x7fffu + ((u >> 16) & 1u);        // RNE, finite inputs only
  return (unsigned short)(u >> 16);
}
__device__ __forceinline__ float bf2f(unsigned short h) {
  union { unsigned u; float f; } v; v.u = ((unsigned)h) << 16;
  return v.f;
}

// ---------------------------------------------------------------------------
// Kernel 0: cast x (2M), qkv_w (3M), c_proj_w (1M) fp32 -> bf16 into one
// contiguous ws region. 1572864 float4 quads total.
// ---------------------------------------------------------------------------
__global__ __launch_bounds__(256) void cast3_kernel(
    const float* __restrict__ x, const float* __restrict__ w1,
    const float* __restrict__ w2, unsigned short* __restrict__ o) {
  long q = (long)blockIdx.x * 256 + threadIdx.x;   // quad index
  const float* src;
  if (q < 524288)        src = x  + 4 * q;
  else if (q < 1310720)  src = w1 + 4 * (q - 524288);
  else                   src = w2 + 4 * (q - 1310720);
  float4v v = *(const float4v*)src;
  ushort4v r;
  r[0] = f2bf(v[0]); r[1] = f2bf(v[1]); r[2] = f2bf(v[2]); r[3] = f2bf(v[3]);
  *(ushort4v*)(o + 4 * q) = r;
}

// ---------------------------------------------------------------------------
// GEMM (BT): C[M,N] = A[M,K] * B[N,K]^T, A/B bf16, acc fp32.
// 128x128 tile per 256-thread block (4 waves in 2x2, 64x64 per wave,
// 4x4 MFMA tiles), K-step 32. LDS row stride 40 bf16 (16B aligned, ~2-way).
// OUT_BF16: write bf16 (qkv intermediate) else fp32 (d_out).
// ---------------------------------------------------------------------------
template <bool OUT_BF16>
__global__ __launch_bounds__(256) void gemm_bt(
    const unsigned short* __restrict__ A, const unsigned short* __restrict__ B,
    void* __restrict__ Cp, int M, int N, int K) {
  __shared__ unsigned short a_sh[128 * 40];
  __shared__ unsigned short b_sh[128 * 40];
  const int tid = threadIdx.x;
  const int wave = tid >> 6, lane = tid & 63;
  const int ln = lane & 15, quad = lane >> 4;
  const int wm = wave & 1, wn = wave >> 1;
  const long arow0 = (long)blockIdx.y * 128;
  const long brow0 = (long)blockIdx.x * 128;
  const int srow = tid >> 1;             // 0..127
  const int scol = (tid & 1) * 16;       // 0 / 16
  const unsigned short* Aptr = A + (arow0 + srow) * (long)K + scol;
  const unsigned short* Bptr = B + (brow0 + srow) * (long)K + scol;
  fx4 acc[4][4] = {};
  for (int k0 = 0; k0 < K; k0 += 32) {
    ushort8 a0 = *(const ushort8*)(Aptr);
    ushort8 a1 = *(const ushort8*)(Aptr + 8);
    ushort8 b0 = *(const ushort8*)(Bptr);
    ushort8 b1 = *(const ushort8*)(Bptr + 8);
    Aptr += 32; Bptr += 32;
    __syncthreads();                     // prior iteration frag reads done
    *(ushort8*)&a_sh[srow * 40 + scol]     = a0;
    *(ushort8*)&a_sh[srow * 40 + scol + 8] = a1;
    *(ushort8*)&b_sh[srow * 40 + scol]     = b0;
    *(ushort8*)&b_sh[srow * 40 + scol + 8] = b1;
    __syncthreads();
    short8 af[4], bfr[4];
    for (int mt = 0; mt < 4; ++mt)
      af[mt] = *(const short8*)&a_sh[(wm * 64 + mt * 16 + ln) * 40 + quad * 8];
    for (int nt = 0; nt < 4; ++nt)
      bfr[nt] = *(const short8*)&b_sh[(wn * 64 + nt * 16 + ln) * 40 + quad * 8];
    for (int mt = 0; mt < 4; ++mt)
      for (int nt = 0; nt < 4; ++nt)
        acc[mt][nt] = __builtin_amdgcn_mfma_f32_16x16x32_bf16(
            af[mt], bfr[nt], acc[mt][nt], 0, 0, 0);
  }
  for (int mt = 0; mt < 4; ++mt)
    for (int nt = 0; nt < 4; ++nt)
      for (int r = 0; r < 4; ++r) {
        long row = arow0 + wm * 64 + mt * 16 + quad * 4 + r;
        long col = brow0 + wn * 64 + nt * 16 + ln;
        float v = acc[mt][nt][r];
        if constexpr (OUT_BF16)
          ((unsigned short*)Cp)[row * N + col] = f2bf(v);
        else
          ((float*)Cp)[row * N + col] = v;
      }
}

// ---------------------------------------------------------------------------
// Kernel 2a: per-row RMSNorm (per head, 128 dims) + rotary for q and k.
// Block = 256 threads = one t-row, thread t: head h=t>>5, c=t&31 handles
// rotary pairs (2c,2c+64) and (2c+1,2c+65). Rotary is linear -> apply rnorm
// after rotation. qhat/khat layout: [h][t][d] bf16.
// ---------------------------------------------------------------------------
__global__ __launch_bounds__(256) void qk_norm_rope(
    const unsigned short* __restrict__ qkv, unsigned short* __restrict__ qh,
    unsigned short* __restrict__ kh) {
  const int t = blockIdx.x;
  const int tid = threadIdx.x;
  const int h = tid >> 5, c = tid & 31;
  float cv[2], sv[2];
  for (int u = 0; u < 2; ++u) {
    int dd = 2 * c + u;
    if (dd < 32) {
      float ang = exp2f(-10.0f * (float)dd / 31.0f);  // (1/1024)^(dd/31)
      float th = (float)t * ang;
      sv[u] = sinf(th); cv[u] = cosf(th);
    } else { sv[u] = 0.f; cv[u] = 1.f; }              // ang = 0
  }
  for (int which = 0; which < 2; ++which) {           // 0 = q, 1 = k
    const unsigned short* src = qkv + (long)t * 3072 + which * 1024 + h * 128;
    ushort2v aa = *(const ushort2v*)(src + 2 * c);
    ushort2v bb = *(const ushort2v*)(src + 64 + 2 * c);
    float x1[2] = { bf2f(aa[0]), bf2f(aa[1]) };
    float x2[2] = { bf2f(bb[0]), bf2f(bb[1]) };
    float ss = x1[0]*x1[0] + x1[1]*x1[1] + x2[0]*x2[0] + x2[1]*x2[1];
    for (int off = 1; off < 32; off <<= 1) ss += __shfl_xor(ss, off);
    float rn = rsqrtf(ss * (1.0f / 128.0f) + 1.1920929e-7f);
    ushort2v o1, o2;
    for (int u = 0; u < 2; ++u) {
      float y1 = ( x1[u] * cv[u] + x2[u] * sv[u]) * rn;
      float y2 = (-x1[u] * sv[u] + x2[u] * cv[u]) * rn;
      o1[u] = f2bf(y1); o2[u] = f2bf(y2);
    }
    unsigned short* dst = (which ? kh : qh) + ((long)h * T_SEQ + t) * 128;
    *(ushort2v*)(dst + 2 * c) = o1;
    *(ushort2v*)(dst + 64 + 2 * c) = o2;
  }
}

// ---------------------------------------------------------------------------
// Kernel 2b: v = l0*v + l1*ve, transposed to vt[h][d][t] bf16 via LDS so the
// attention PV B-fragment (B[k=kv][n=d] = Vt[d][kv]) reads contiguous in k.
// Block = (t-tile 64, head). Thread reads [r=tid>>2][32 d], scatters to
// lds[d][r], then rows d written out coalesced.
// ---------------------------------------------------------------------------
__global__ __launch_bounds__(256) void v_combine_t(
    const unsigned short* __restrict__ qkv, const float* __restrict__ ve,
    const float* __restrict__ lambdas, unsigned short* __restrict__ vt) {
  __shared__ unsigned short lt[128 * 72];
  const int tt = blockIdx.x, h = blockIdx.y;
  const int tid = threadIdx.x;
  const float l0 = lambdas[0], l1 = lambdas[1];
  const int r = tid >> 2, cb = (tid & 3) * 32;
  const unsigned short* vs = qkv + (long)(tt * 64 + r) * 3072 + 2048 + h * 128 + cb;
  const float* es = ve + (long)(tt * 64 + r) * 1024 + h * 128 + cb;
  ushort8 vv[4];
  for (int q = 0; q < 4; ++q) vv[q] = *(const ushort8*)(vs + 8 * q);
  float4v ee[8];
  for (int q = 0; q < 8; ++q) ee[q] = *(const float4v*)(es + 4 * q);
  for (int j = 0; j < 32; ++j) {
    float v = bf2f(vv[j >> 3][j & 7]) * l0 + ee[j >> 2][j & 3] * l1;
    lt[(cb + j) * 72 + r] = f2bf(v);
  }
  __syncthreads();
  const int d = tid >> 1, half = (tid & 1) * 32;
  unsigned short* dst = vt + ((long)h * HD + d) * T_SEQ + tt * 64 + half;
  const unsigned short* srcl = &lt[d * 72 + half];
  *(ushort8*)(dst)      = *(const ushort8*)(srcl);
  *(ushort8*)(dst + 8)  = *(const ushort8*)(srcl + 8);
  *(ushort8*)(dst + 16) = *(const ushort8*)(srcl + 16);
  *(ushort8*)(dst + 24) = *(const ushort8*)(srcl + 24);
}

// ---------------------------------------------------------------------------
// Kernel 3: flash attention. Block = (q-tile 64, head), 4 waves x 16 q-rows.
// Per kv-tile (64): S = Q*K^T (16 MFMA/wave), online softmax in C-layout,
// P -> per-wave LDS (bf16) -> A-frags, Y += P*V (16 MFMA/wave).
// y layout: [t][h*128+d] bf16 (feeds proj GEMM directly).
// ---------------------------------------------------------------------------
__global__ __launch_bounds__(256) void attn_kernel(
    const unsigned short* __restrict__ qh, const unsigned short* __restrict__ kh,
    const unsigned short* __restrict__ vt, unsigned short* __restrict__ y) {
  __shared__ unsigned short k_sh[64 * 136];   // [kv][d], stride 136
  __shared__ unsigned short v_sh[128 * 72];   // [d][kv], stride 72
  __shared__ unsigned short p_sh[4][16 * 72]; // per-wave P [qrow][kv]
  const int tid = threadIdx.x;
  const int wave = tid >> 6, lane = tid & 63;
  const int ln = lane & 15, quad = lane >> 4;
  const int qt = blockIdx.x, h = blockIdx.y;
  const int qrow0 = qt * 64 + wave * 16;

  short8 qf[4];
  {
    const unsigned short* qbase = qh + ((long)h * T_SEQ + qrow0 + ln) * 128;
    for (int kc = 0; kc < 4; ++kc)
      qf[kc] = *(const short8*)(qbase + kc * 32 + quad * 8);
  }
  fx4 accy[8] = {};
  float m_i[4], l_i[4];
  for (int r = 0; r < 4; ++r) { m_i[r] = -1e30f; l_i[r] = 0.f; }

  const int kr = tid >> 2, kcb = (tid & 3) * 32;   // K staging
  const int vr = tid >> 1, vhb = (tid & 1) * 32;   // V staging

  for (int jt = 0; jt <= qt; ++jt) {
    __syncthreads();
    {
      const unsigned short* src = kh + ((long)h * T_SEQ + jt * 64 + kr) * 128 + kcb;
      ushort8 t0 = *(const ushort8*)(src);
      ushort8 t1 = *(const ushort8*)(src + 8);
      ushort8 t2 = *(const ushort8*)(src + 16);
      ushort8 t3 = *(const ushort8*)(src + 24);
      unsigned short* d0 = &k_sh[kr * 136 + kcb];
      *(ushort8*)(d0) = t0; *(ushort8*)(d0 + 8) = t1;
      *(ushort8*)(d0 + 16) = t2; *(ushort8*)(d0 + 24) = t3;
      const unsigned short* sv2 = vt + ((long)h * HD + vr) * T_SEQ + jt * 64 + vhb;
      ushort8 u0 = *(const ushort8*)(sv2);
      ushort8 u1 = *(const ushort8*)(sv2 + 8);
      ushort8 u2 = *(const ushort8*)(sv2 + 16);
      ushort8 u3 = *(const ushort8*)(sv2 + 24);
      unsigned short* d1 = &v_sh[vr * 72 + vhb];
      *(ushort8*)(d1) = u0; *(ushort8*)(d1 + 8) = u1;
      *(ushort8*)(d1 + 16) = u2; *(ushort8*)(d1 + 24) = u3;
    }
    __syncthreads();

    fx4 s[4];
    for (int nt = 0; nt < 4; ++nt) {
      fx4 c = {0.f, 0.f, 0.f, 0.f};
      for (int kc = 0; kc < 4; ++kc) {
        short8 kb = *(const short8*)&k_sh[(nt * 16 + ln) * 136 + kc * 32 + quad * 8];
        c = __builtin_amdgcn_mfma_f32_16x16x32_bf16(qf[kc], kb, c, 0, 0, 0);
      }
      s[nt] = c;
    }
    const bool diag = (jt == qt);
    float p[4][4], mx[4];
    for (int r = 0; r < 4; ++r) mx[r] = -1e30f;
    for (int nt = 0; nt < 4; ++nt) {
      int col = jt * 64 + nt * 16 + ln;
      for (int r = 0; r < 4; ++r) {
        int row = qrow0 + quad * 4 + r;
        float svv = s[nt][r] * 0.12f;
        if (diag && col > row) svv = -1e30f;
        p[nt][r] = svv;
        mx[r] = fmaxf(mx[r], svv);
      }
    }
    for (int r = 0; r < 4; ++r) {
      float m = mx[r];
      for (int off = 1; off < 16; off <<= 1) m = fmaxf(m, __shfl_xor(m, off));
      float mn = fmaxf(m_i[r], m);
      float alpha = __expf(m_i[r] - mn);
      m_i[r] = mn;
      float rs = 0.f;
      for (int nt = 0; nt < 4; ++nt) {
        float pv = __expf(p[nt][r] - mn);
        p[nt][r] = pv;
        rs += pv;
      }
      for (int off = 1; off < 16; off <<= 1) rs += __shfl_xor(rs, off);
      l_i[r] = l_i[r] * alpha + rs;
      for (int ntd = 0; ntd < 8; ++ntd) accy[ntd][r] *= alpha;
    }
    // P (C-layout) -> per-wave LDS -> A-operand layout
    for (int nt = 0; nt < 4; ++nt)
      for (int r = 0; r < 4; ++r)
        p_sh[wave][(quad * 4 + r) * 72 + nt * 16 + ln] = f2bf(p[nt][r]);
    for (int kc2 = 0; kc2 < 2; ++kc2) {
      short8 pa = *(const short8*)&p_sh[wave][ln * 72 + kc2 * 32 + quad * 8];
      for (int ntd = 0; ntd < 8; ++ntd) {
        short8 vb = *(const short8*)&v_sh[(ntd * 16 + ln) * 72 + kc2 * 32 + quad * 8];
        accy[ntd] = __builtin_amdgcn_mfma_f32_16x16x32_bf16(pa, vb, accy[ntd], 0, 0, 0);
      }
    }
  }
  for (int r = 0; r < 4; ++r) {
    float inv = 1.0f / l_i[r];
    long row = qrow0 + quad * 4 + r;
    for (int ntd = 0; ntd < 8; ++ntd)
      y[row * 1024 + h * 128 + ntd * 16 + ln] = f2bf(accy[ntd][r] * inv);
  }
}

// ---------------------------------------------------------------------------
// Workspace layout (bytes), total 40 MB:
//   0        : qkv_bf   [2048][3072] bf16   (12.0 MB)
//   12582912 : x_bf     [2048][1024] bf16   ( 4.0 MB)  \
//   16777216 : wqkv_bf  [3072][1024] bf16   ( 6.0 MB)   } contiguous cast dst
//   23068672 : wproj_bf [1024][1024] bf16   ( 2.0 MB)  /
//   25165824 : qhat     [8][2048][128] bf16 ( 4.0 MB)
//   29360128 : khat     [8][2048][128] bf16 ( 4.0 MB)
//   33554432 : vt       [8][128][2048] bf16 ( 4.0 MB)
//   37748736 : y_bf     [2048][1024] bf16   ( 4.0 MB)
// ---------------------------------------------------------------------------
extern "C" void kernel_launch(void* const* d_in, const int* in_sizes, int n_in,
                              void* d_out, int out_size, void* d_ws, size_t ws_size,
                              hipStream_t stream) {
  const float* x       = (const float*)d_in[0];
  const float* ve      = (const float*)d_in[1];
  const float* qkv_w   = (const float*)d_in[2];
  const float* lambdas = (const float*)d_in[3];
  const float* c_proj  = (const float*)d_in[4];
  char* ws = (char*)d_ws;
  unsigned short* qkv_bf = (unsigned short*)(ws);
  unsigned short* x_bf   = (unsigned short*)(ws + 12582912);
  unsigned short* wqkv   = (unsigned short*)(ws + 16777216);
  unsigned short* wproj  = (unsigned short*)(ws + 23068672);
  unsigned short* qhat   = (unsigned short*)(ws + 25165824);
  unsigned short* khat   = (unsigned short*)(ws + 29360128);
  unsigned short* vtb    = (unsigned short*)(ws + 33554432);
  unsigned short* ybf    = (unsigned short*)(ws + 37748736);
  float* out = (float*)d_out;

  cast3_kernel<<<6144, 256, 0, stream>>>(x, qkv_w, c_proj, x_bf);
  gemm_bt<true><<<dim3(24, 16), 256, 0, stream>>>(x_bf, wqkv, qkv_bf, 2048, 3072, 1024);
  qk_norm_rope<<<2048, 256, 0, stream>>>(qkv_bf, qhat, khat);
  v_combine_t<<<dim3(32, 8), 256, 0, stream>>>(qkv_bf, ve, lambdas, vtb);
  attn_kernel<<<dim3(32, 8), 256, 0, stream>>>(qhat, khat, vtb, ybf);
  gemm_bt<false><<<dim3(8, 16), 256, 0, stream>>>(ybf, wproj, out, 2048, 1024, 1024);
}

// Round 2
// 221.572 us; speedup vs baseline: 1.1301x; 1.1301x over previous
//
#include <hip/hip_runtime.h>

// ---------------------------------------------------------------------------
// CausalSelfAttention (B=1, T=2048, DIM=1024, H=8, hd=128, scale=0.12)
// R2: chunked flash-decoding attention (fixed-max softmax, no in-loop
//     shuffles) + m97-style GEMM (global_load_lds width=16, XOR swizzle).
// MFMA layouts (verified per guide m89/m91/m120):
//   A[m=lane&15][k=quad*8+j], B[k=quad*8+j][n=lane&15],
//   C/D: row=quad*4+reg, col=lane&15   (quad = lane>>4)
// ---------------------------------------------------------------------------

typedef __attribute__((ext_vector_type(8))) short short8;      // 8 bf16 (4 VGPR)
typedef __attribute__((ext_vector_type(4))) float fx4;         // MFMA acc
typedef __attribute__((ext_vector_type(8))) unsigned short ushort8;
typedef __attribute__((ext_vector_type(4))) unsigned short ushort4v;
typedef __attribute__((ext_vector_type(2))) unsigned short ushort2v;
typedef __attribute__((ext_vector_type(4))) float float4v;

#define T_SEQ 2048
#define NH 8
#define HD 128

__device__ __forceinline__ unsigned short f2bf(float f) {
  union { float f; unsigned u; } v; v.f = f;
  unsigned u = v.u;
  u += 0x7fffu + ((u >> 16) & 1u);        // RNE, finite inputs only
  return (unsigned short)(u >> 16);
}
__device__ __forceinline__ unsigned short f2bf_t(float f) {  // truncate (fast)
  union { float f; unsigned u; } v; v.f = f;
  return (unsigned short)(v.u >> 16);
}
__device__ __forceinline__ float bf2f(unsigned short h) {
  union { unsigned u; float f; } v; v.u = ((unsigned)h) << 16;
  return v.f;
}

// async global->LDS, 16B per lane; LDS dest is wave-uniform base + lane*16
typedef __attribute__((address_space(1))) unsigned int glb_u32;
typedef __attribute__((address_space(3))) unsigned int lds_u32;
__device__ __forceinline__ void gl_lds16(const unsigned short* g, unsigned short* l) {
  __builtin_amdgcn_global_load_lds((const glb_u32*)g, (lds_u32*)l, 16, 0, 0);
}

// ---------------------------------------------------------------------------
// Kernel 0: cast x (2M), qkv_w (3M), c_proj_w (1M) fp32 -> bf16 contiguous.
// ---------------------------------------------------------------------------
__global__ __launch_bounds__(256) void cast3_kernel(
    const float* __restrict__ x, const float* __restrict__ w1,
    const float* __restrict__ w2, unsigned short* __restrict__ o) {
  long q = (long)blockIdx.x * 256 + threadIdx.x;   // quad index
  const float* src;
  if (q < 524288)        src = x  + 4 * q;
  else if (q < 1310720)  src = w1 + 4 * (q - 524288);
  else                   src = w2 + 4 * (q - 1310720);
  float4v v = *(const float4v*)src;
  ushort4v r;
  r[0] = f2bf(v[0]); r[1] = f2bf(v[1]); r[2] = f2bf(v[2]); r[3] = f2bf(v[3]);
  *(ushort4v*)(o + 4 * q) = r;
}

// ---------------------------------------------------------------------------
// GEMM (BT): C[M,N] = A[M,K]*B[N,K]^T, bf16 in / fp32 acc. 128x128 tile,
// BK=32, 4 waves (2x2 of 64x64). Staging via global_load_lds width=16:
// LDS unpadded [128][32] shorts; chunk (16B) at logical k-chunk c of row m
// stored at position c ^ ((m>>1)&3)  -> 2-way banks on ds_read_b128 (free).
// Each wave issues 4 loads (1KB each, uniform LDS base, HW adds lane*16).
// ---------------------------------------------------------------------------
template <bool OUT_BF16>
__global__ __launch_bounds__(256) void gemm_bt2(
    const unsigned short* __restrict__ A, const unsigned short* __restrict__ B,
    void* __restrict__ Cp, int M, int N, int K) {
  __shared__ unsigned short a_sh[128 * 32];
  __shared__ unsigned short b_sh[128 * 32];
  const int tid = threadIdx.x;
  const int wave = tid >> 6, lane = tid & 63;
  const int ln = lane & 15, quad = lane >> 4;
  const int wm = wave & 1, wn = wave >> 1;
  const long arow0 = (long)blockIdx.y * 128;
  const long brow0 = (long)blockIdx.x * 128;

  const unsigned short* gsrc[4];
  unsigned short* ldst[4];
  for (int i = 0; i < 4; ++i) {
    int s = wave * 4 + i;                 // segment 0..15 (wave-uniform)
    int li = s * 64 + lane;               // linear chunk 0..1023
    int isB = li >> 9;
    int ci = li & 511;                    // chunk within region
    int m = ci >> 2, p = ci & 3;
    int cch = p ^ ((m >> 1) & 3);         // which global chunk lands here
    const unsigned short* Gb = isB ? (B + brow0 * (long)K) : (A + arow0 * (long)K);
    gsrc[i] = Gb + (long)m * K + cch * 8;
    ldst[i] = (isB ? b_sh : a_sh) + (s & 7) * 512;   // uniform segment base
  }

  fx4 acc[4][4] = {};
  for (int k0 = 0; k0 < K; k0 += 32) {
    __syncthreads();                      // prev-iter frag reads complete
    for (int i = 0; i < 4; ++i)
      gl_lds16(gsrc[i] + k0, ldst[i]);
    __syncthreads();                      // drains vmcnt -> LDS ready
    short8 af[4], bfr[4];
    for (int mt = 0; mt < 4; ++mt) {
      int m = wm * 64 + mt * 16 + ln;
      int pos = quad ^ ((m >> 1) & 3);
      af[mt] = *(const short8*)&a_sh[m * 32 + pos * 8];
    }
    for (int nt = 0; nt < 4; ++nt) {
      int m = wn * 64 + nt * 16 + ln;
      int pos = quad ^ ((m >> 1) & 3);
      bfr[nt] = *(const short8*)&b_sh[m * 32 + pos * 8];
    }
    for (int mt = 0; mt < 4; ++mt)
      for (int nt = 0; nt < 4; ++nt)
        acc[mt][nt] = __builtin_amdgcn_mfma_f32_16x16x32_bf16(
            af[mt], bfr[nt], acc[mt][nt], 0, 0, 0);
  }
  for (int mt = 0; mt < 4; ++mt)
    for (int nt = 0; nt < 4; ++nt)
      for (int r = 0; r < 4; ++r) {
        long row = arow0 + wm * 64 + mt * 16 + quad * 4 + r;
        long col = brow0 + wn * 64 + nt * 16 + ln;
        float v = acc[mt][nt][r];
        if constexpr (OUT_BF16)
          ((unsigned short*)Cp)[row * N + col] = f2bf(v);
        else
          ((float*)Cp)[row * N + col] = v;
      }
}

// ---------------------------------------------------------------------------
// Kernel 2a: per-head RMSNorm + rotary for q,k. qhat/khat: [h][t][d] bf16.
// ---------------------------------------------------------------------------
__global__ __launch_bounds__(256) void qk_norm_rope(
    const unsigned short* __restrict__ qkv, unsigned short* __restrict__ qh,
    unsigned short* __restrict__ kh) {
  const int t = blockIdx.x;
  const int tid = threadIdx.x;
  const int h = tid >> 5, c = tid & 31;
  float cv[2], sv[2];
  for (int u = 0; u < 2; ++u) {
    int dd = 2 * c + u;
    if (dd < 32) {
      float ang = exp2f(-10.0f * (float)dd / 31.0f);  // (1/1024)^(dd/31)
      float th = (float)t * ang;
      sv[u] = __sinf(th); cv[u] = __cosf(th);
    } else { sv[u] = 0.f; cv[u] = 1.f; }              // ang = 0
  }
  for (int which = 0; which < 2; ++which) {           // 0 = q, 1 = k
    const unsigned short* src = qkv + (long)t * 3072 + which * 1024 + h * 128;
    ushort2v aa = *(const ushort2v*)(src + 2 * c);
    ushort2v bb = *(const ushort2v*)(src + 64 + 2 * c);
    float x1[2] = { bf2f(aa[0]), bf2f(aa[1]) };
    float x2[2] = { bf2f(bb[0]), bf2f(bb[1]) };
    float ss = x1[0]*x1[0] + x1[1]*x1[1] + x2[0]*x2[0] + x2[1]*x2[1];
    for (int off = 1; off < 32; off <<= 1) ss += __shfl_xor(ss, off);
    float rn = rsqrtf(ss * (1.0f / 128.0f) + 1.1920929e-7f);
    ushort2v o1, o2;
    for (int u = 0; u < 2; ++u) {
      float y1 = ( x1[u] * cv[u] + x2[u] * sv[u]) * rn;
      float y2 = (-x1[u] * sv[u] + x2[u] * cv[u]) * rn;
      o1[u] = f2bf(y1); o2[u] = f2bf(y2);
    }
    unsigned short* dst = (which ? kh : qh) + ((long)h * T_SEQ + t) * 128;
    *(ushort2v*)(dst + 2 * c) = o1;
    *(ushort2v*)(dst + 64 + 2 * c) = o2;
  }
}

// ---------------------------------------------------------------------------
// Kernel 2b: v = l0*v + l1*ve, transpose to vt[h][d][t] bf16 via LDS.
// ---------------------------------------------------------------------------
__global__ __launch_bounds__(256) void v_combine_t(
    const unsigned short* __restrict__ qkv, const float* __restrict__ ve,
    const float* __restrict__ lambdas, unsigned short* __restrict__ vt) {
  __shared__ unsigned short lt[128 * 72];
  const int tt = blockIdx.x, h = blockIdx.y;
  const int tid = threadIdx.x;
  const float l0 = lambdas[0], l1 = lambdas[1];
  const int r = tid >> 2, cb = (tid & 3) * 32;
  const unsigned short* vs = qkv + (long)(tt * 64 + r) * 3072 + 2048 + h * 128 + cb;
  const float* es = ve + (long)(tt * 64 + r) * 1024 + h * 128 + cb;
  ushort8 vv[4];
  for (int q = 0; q < 4; ++q) vv[q] = *(const ushort8*)(vs + 8 * q);
  float4v ee[8];
  for (int q = 0; q < 8; ++q) ee[q] = *(const float4v*)(es + 4 * q);
  for (int j = 0; j < 32; ++j) {
    float v = bf2f(vv[j >> 3][j & 7]) * l0 + ee[j >> 2][j & 3] * l1;
    lt[(cb + j) * 72 + r] = f2bf(v);
  }
  __syncthreads();
  const int d = tid >> 1, half = (tid & 1) * 32;
  unsigned short* dst = vt + ((long)h * HD + d) * T_SEQ + tt * 64 + half;
  const unsigned short* srcl = &lt[d * 72 + half];
  *(ushort8*)(dst)      = *(const ushort8*)(srcl);
  *(ushort8*)(dst + 8)  = *(const ushort8*)(srcl + 8);
  *(ushort8*)(dst + 16) = *(const ushort8*)(srcl + 16);
  *(ushort8*)(dst + 24) = *(const ushort8*)(srcl + 24);
}

// ---------------------------------------------------------------------------
// Kernel 3a: chunked flash attention partials. Grid (qt=32, h=8, chunk=4),
// chunk c covers kv-tiles [8c, min(8c+7, qt)]; inactive blocks exit.
// Fixed-max softmax: q,k RMS-normed => |s| <= 128, scaled <= 15.4 < 16.
//   p = exp2(s*0.12*log2e - 16*log2e); masked -> 0.  No running max, no
//   alpha rescale, l accumulates per-lane (reduced across 16 lanes at end).
// Partials: Yp bf16 [pidx][64][128], lp fp32 [pidx][64], pidx=((h*32+qt)*4+c).
// ---------------------------------------------------------------------------
#define ATT_C1 0.17312340490667562f   // 0.12 * log2(e)
#define ATT_C2 23.083120654223415f    // 16   * log2(e)

__global__ __launch_bounds__(256) void attn_part(
    const unsigned short* __restrict__ qh, const unsigned short* __restrict__ kh,
    const unsigned short* __restrict__ vt, unsigned short* __restrict__ Yp,
    float* __restrict__ lp) {
  __shared__ unsigned short k_sh[64 * 136];   // [kv][d]
  __shared__ unsigned short v_sh[128 * 72];   // [d][kv]
  __shared__ unsigned short p_sh[4][16 * 72]; // per-wave P [qrow][kv]
  const int tid = threadIdx.x;
  const int wave = tid >> 6, lane = tid & 63;
  const int ln = lane & 15, quad = lane >> 4;
  const int qt = blockIdx.x, h = blockIdx.y, ch = blockIdx.z;
  const int j0 = ch * 8;
  if (j0 > qt) return;                        // uniform per block
  const int j1 = min(j0 + 7, qt);
  const int qrow0 = qt * 64 + wave * 16;

  short8 qf[4];
  {
    const unsigned short* qbase = qh + ((long)h * T_SEQ + qrow0 + ln) * 128;
    for (int kc = 0; kc < 4; ++kc)
      qf[kc] = *(const short8*)(qbase + kc * 32 + quad * 8);
  }
  fx4 accy[8] = {};
  float l_loc[4] = {0.f, 0.f, 0.f, 0.f};

  const int kr = tid >> 2, kcb = (tid & 3) * 32;
  const int vr = tid >> 1, vhb = (tid & 1) * 32;

  for (int jt = j0; jt <= j1; ++jt) {
    __syncthreads();
    {
      const unsigned short* src = kh + ((long)h * T_SEQ + jt * 64 + kr) * 128 + kcb;
      ushort8 t0 = *(const ushort8*)(src);
      ushort8 t1 = *(const ushort8*)(src + 8);
      ushort8 t2 = *(const ushort8*)(src + 16);
      ushort8 t3 = *(const ushort8*)(src + 24);
      unsigned short* d0 = &k_sh[kr * 136 + kcb];
      *(ushort8*)(d0) = t0; *(ushort8*)(d0 + 8) = t1;
      *(ushort8*)(d0 + 16) = t2; *(ushort8*)(d0 + 24) = t3;
      const unsigned short* sv2 = vt + ((long)h * HD + vr) * T_SEQ + jt * 64 + vhb;
      ushort8 u0 = *(const ushort8*)(sv2);
      ushort8 u1 = *(const ushort8*)(sv2 + 8);
      ushort8 u2 = *(const ushort8*)(sv2 + 16);
      ushort8 u3 = *(const ushort8*)(sv2 + 24);
      unsigned short* d1 = &v_sh[vr * 72 + vhb];
      *(ushort8*)(d1) = u0; *(ushort8*)(d1 + 8) = u1;
      *(ushort8*)(d1 + 16) = u2; *(ushort8*)(d1 + 24) = u3;
    }
    __syncthreads();

    fx4 s[4];
    for (int nt = 0; nt < 4; ++nt) {
      fx4 c = {0.f, 0.f, 0.f, 0.f};
      for (int kc = 0; kc < 4; ++kc) {
        short8 kb = *(const short8*)&k_sh[(nt * 16 + ln) * 136 + kc * 32 + quad * 8];
        c = __builtin_amdgcn_mfma_f32_16x16x32_bf16(qf[kc], kb, c, 0, 0, 0);
      }
      s[nt] = c;
    }
    const bool diag = (jt == qt);
    float p[4][4];
    for (int nt = 0; nt < 4; ++nt) {
      int col = jt * 64 + nt * 16 + ln;
      for (int r = 0; r < 4; ++r) {
        float pv = exp2f(fmaf(s[nt][r], ATT_C1, -ATT_C2));
        if (diag && col > (qrow0 + quad * 4 + r)) pv = 0.f;
        p[nt][r] = pv;
      }
    }
    for (int r = 0; r < 4; ++r)
      l_loc[r] += (p[0][r] + p[1][r]) + (p[2][r] + p[3][r]);
    // P (C-layout) -> per-wave LDS -> A-operand layout
    for (int nt = 0; nt < 4; ++nt)
      for (int r = 0; r < 4; ++r)
        p_sh[wave][(quad * 4 + r) * 72 + nt * 16 + ln] = f2bf_t(p[nt][r]);
    for (int kc2 = 0; kc2 < 2; ++kc2) {
      short8 pa = *(const short8*)&p_sh[wave][ln * 72 + kc2 * 32 + quad * 8];
      for (int ntd = 0; ntd < 8; ++ntd) {
        short8 vb = *(const short8*)&v_sh[(ntd * 16 + ln) * 72 + kc2 * 32 + quad * 8];
        accy[ntd] = __builtin_amdgcn_mfma_f32_16x16x32_bf16(pa, vb, accy[ntd], 0, 0, 0);
      }
    }
  }

  const long pidx = (long)((h * 32 + qt) * 4 + ch);
  unsigned short* yb = Yp + pidx * 8192;
  for (int r = 0; r < 4; ++r) {
    float l = l_loc[r];
    for (int off = 1; off < 16; off <<= 1) l += __shfl_xor(l, off);
    int row = wave * 16 + quad * 4 + r;
    if (ln == 0) lp[pidx * 64 + row] = l;
    for (int ntd = 0; ntd < 8; ++ntd)
      yb[row * 128 + ntd * 16 + ln] = f2bf(accy[ntd][r]);
  }
}

// ---------------------------------------------------------------------------
// Kernel 3b: combine chunk partials: Y = (sum_c Yp) / (sum_c lp), write
// ybf [t][h*128+d] bf16. Block per (qt, h); thread: row=tid>>2, 32 cols.
// ---------------------------------------------------------------------------
__global__ __launch_bounds__(256) void attn_combine(
    const unsigned short* __restrict__ Yp, const float* __restrict__ lp,
    unsigned short* __restrict__ y) {
  const int qt = blockIdx.x, h = blockIdx.y;
  const int tid = threadIdx.x;
  const int row = tid >> 2, cb = (tid & 3) * 32;
  const int nc = (qt >> 3) + 1;
  float acc[32];
  for (int j = 0; j < 32; ++j) acc[j] = 0.f;
  float ltot = 0.f;
  for (int c = 0; c < nc; ++c) {
    long pidx = (long)((h * 32 + qt) * 4 + c);
    const unsigned short* ys = Yp + pidx * 8192 + row * 128 + cb;
    ltot += lp[pidx * 64 + row];
    for (int q8 = 0; q8 < 4; ++q8) {
      ushort8 v = *(const ushort8*)(ys + q8 * 8);
      for (int j = 0; j < 8; ++j) acc[q8 * 8 + j] += bf2f(v[j]);
    }
  }
  float inv = 1.f / ltot;
  unsigned short* dst = y + (long)(qt * 64 + row) * 1024 + h * 128 + cb;
  for (int q8 = 0; q8 < 4; ++q8) {
    ushort8 o;
    for (int j = 0; j < 8; ++j) o[j] = f2bf(acc[q8 * 8 + j] * inv);
    *(ushort8*)(dst + q8 * 8) = o;
  }
}

// ---------------------------------------------------------------------------
// Workspace layout (bytes), ~42 MB. Attention partials reuse regions that
// are dead by the time attn_part runs (qkv_bf/x_bf/wqkv consumed earlier).
//   0        : qkv_bf [2048][3072] bf16 (12MB)   | later: Yp bf16 16MB (0..16M)
//   12582912 : x_bf   [2048][1024] bf16 ( 4MB)   |   (overlaps Yp tail)
//   16777216 : wqkv   [3072][1024] bf16 ( 6MB)   | later: lp fp32 256KB
//   23068672 : wproj  [1024][1024] bf16 ( 2MB)   (live until GEMM2)
//   25165824 : qhat   [8][2048][128] bf16 (4MB)
//   29360128 : khat   [8][2048][128] bf16 (4MB)
//   33554432 : vt     [8][128][2048] bf16 (4MB)
//   37748736 : ybf    [2048][1024] bf16 (4MB)
// ---------------------------------------------------------------------------
extern "C" void kernel_launch(void* const* d_in, const int* in_sizes, int n_in,
                              void* d_out, int out_size, void* d_ws, size_t ws_size,
                              hipStream_t stream) {
  const float* x       = (const float*)d_in[0];
  const float* ve      = (const float*)d_in[1];
  const float* qkv_w   = (const float*)d_in[2];
  const float* lambdas = (const float*)d_in[3];
  const float* c_proj  = (const float*)d_in[4];
  char* ws = (char*)d_ws;
  unsigned short* qkv_bf = (unsigned short*)(ws);
  unsigned short* x_bf   = (unsigned short*)(ws + 12582912);
  unsigned short* wqkv   = (unsigned short*)(ws + 16777216);
  unsigned short* wproj  = (unsigned short*)(ws + 23068672);
  unsigned short* qhat   = (unsigned short*)(ws + 25165824);
  unsigned short* khat   = (unsigned short*)(ws + 29360128);
  unsigned short* vtb    = (unsigned short*)(ws + 33554432);
  unsigned short* ybf    = (unsigned short*)(ws + 37748736);
  unsigned short* Yp     = (unsigned short*)(ws);              // reuse, 16MB
  float*          lpart  = (float*)(ws + 16777216);            // reuse, 256KB
  float* out = (float*)d_out;

  cast3_kernel<<<6144, 256, 0, stream>>>(x, qkv_w, c_proj, x_bf);
  gemm_bt2<true><<<dim3(24, 16), 256, 0, stream>>>(x_bf, wqkv, qkv_bf, 2048, 3072, 1024);
  qk_norm_rope<<<2048, 256, 0, stream>>>(qkv_bf, qhat, khat);
  v_combine_t<<<dim3(32, 8), 256, 0, stream>>>(qkv_bf, ve, lambdas, vtb);
  attn_part<<<dim3(32, 8, 4), 256, 0, stream>>>(qhat, khat, vtb, Yp, lpart);
  attn_combine<<<dim3(32, 8), 256, 0, stream>>>(Yp, lpart, ybf);
  gemm_bt2<false><<<dim3(8, 16), 256, 0, stream>>>(ybf, wproj, out, 2048, 1024, 1024);
}

// Round 3
// 213.142 us; speedup vs baseline: 1.1748x; 1.0396x over previous
//
#include <hip/hip_runtime.h>

// ---------------------------------------------------------------------------
// CausalSelfAttention (B=1, T=2048, DIM=1024, H=8, hd=128, scale=0.12)
// R3: attention computes S^T = K*Q^T (swap MFMA operands) so the PV
//     B-operand (P^T) is built by quad-shuffles (no LDS round-trip);
//     K/V prefetched into VGPRs one tile ahead; 5 chunks of 7 kv-tiles;
//     gemm2 retiled to 128x64 (256 blocks).
// MFMA layouts (m89/m91/m120): A[m=lane&15][k=quad*8+j],
//   B[k=quad*8+j][n=lane&15], C/D: row=quad*4+reg, col=lane&15 (quad=lane>>4)
// ---------------------------------------------------------------------------

typedef __attribute__((ext_vector_type(8))) short short8;      // 8 bf16
typedef __attribute__((ext_vector_type(4))) float fx4;         // MFMA acc
typedef __attribute__((ext_vector_type(8))) unsigned short ushort8;
typedef __attribute__((ext_vector_type(4))) unsigned short ushort4v;
typedef __attribute__((ext_vector_type(2))) unsigned short ushort2v;
typedef __attribute__((ext_vector_type(4))) float float4v;

#define T_SEQ 2048
#define NH 8
#define HD 128
#define NCH 5      // kv chunks per q-tile
#define CHW 7      // kv-tiles per chunk

__device__ __forceinline__ unsigned short f2bf(float f) {
  union { float f; unsigned u; } v; v.f = f;
  unsigned u = v.u;
  u += 0x7fffu + ((u >> 16) & 1u);        // RNE, finite inputs only
  return (unsigned short)(u >> 16);
}
__device__ __forceinline__ unsigned f2bf2_t(float lo, float hi) { // pack trunc
  union { float f; unsigned u; } a, b; a.f = lo; b.f = hi;
  return (a.u >> 16) | (b.u & 0xffff0000u);
}
__device__ __forceinline__ float bf2f(unsigned short h) {
  union { unsigned u; float f; } v; v.u = ((unsigned)h) << 16;
  return v.f;
}

// async global->LDS, 16B/lane; LDS dest = wave-uniform base + lane*16
typedef __attribute__((address_space(1))) unsigned int glb_u32;
typedef __attribute__((address_space(3))) unsigned int lds_u32;
__device__ __forceinline__ void gl_lds16(const unsigned short* g, unsigned short* l) {
  __builtin_amdgcn_global_load_lds((const glb_u32*)g, (lds_u32*)l, 16, 0, 0);
}

// ---------------------------------------------------------------------------
// Kernel 0: cast x (2M), qkv_w (3M), c_proj_w (1M) fp32 -> bf16 contiguous.
// ---------------------------------------------------------------------------
__global__ __launch_bounds__(256) void cast3_kernel(
    const float* __restrict__ x, const float* __restrict__ w1,
    const float* __restrict__ w2, unsigned short* __restrict__ o) {
  long q = (long)blockIdx.x * 256 + threadIdx.x;   // quad index
  const float* src;
  if (q < 524288)        src = x  + 4 * q;
  else if (q < 1310720)  src = w1 + 4 * (q - 524288);
  else                   src = w2 + 4 * (q - 1310720);
  float4v v = *(const float4v*)src;
  ushort4v r;
  r[0] = f2bf(v[0]); r[1] = f2bf(v[1]); r[2] = f2bf(v[2]); r[3] = f2bf(v[3]);
  *(ushort4v*)(o + 4 * q) = r;
}

// ---------------------------------------------------------------------------
// GEMM (BT): C[M,N] = A[M,K]*B[N,K]^T, bf16 in / fp32 acc. Tile 128 x BN,
// BK=32, 4 waves (2x2, wave tile 64 x BN/2). global_load_lds width=16;
// LDS unpadded [rows][32]; 16B chunk c of row m at pos c ^ ((m>>1)&3).
// ---------------------------------------------------------------------------
template <bool OUT_BF16, int BN>
__global__ __launch_bounds__(256) void gemm_bt2(
    const unsigned short* __restrict__ A, const unsigned short* __restrict__ B,
    void* __restrict__ Cp, int M, int N, int K) {
  constexpr int NT = BN / 32;                 // n-tiles per wave
  constexpr int NLOAD = (512 + BN * 4) / 256; // gl_lds16 per thread
  __shared__ unsigned short a_sh[128 * 32];
  __shared__ unsigned short b_sh[BN * 32];
  const int tid = threadIdx.x;
  const int wave = tid >> 6, lane = tid & 63;
  const int ln = lane & 15, quad = lane >> 4;
  const int wm = wave & 1, wn = wave >> 1;
  const long arow0 = (long)blockIdx.y * 128;
  const long brow0 = (long)blockIdx.x * BN;

  const unsigned short* gsrc[NLOAD];
  unsigned short* ldst[NLOAD];
  for (int i = 0; i < NLOAD; ++i) {
    int s = wave * NLOAD + i;             // segment (wave-uniform)
    int li = s * 64 + lane;               // linear chunk
    int isB = li >= 512;
    int ci = isB ? li - 512 : li;
    int m = ci >> 2, p = ci & 3;
    int cch = p ^ ((m >> 1) & 3);
    const unsigned short* Gb = isB ? (B + brow0 * (long)K) : (A + arow0 * (long)K);
    gsrc[i] = Gb + (long)m * K + cch * 8;
    ldst[i] = isB ? (b_sh + (s - 8) * 512) : (a_sh + s * 512);
  }

  fx4 acc[4][NT] = {};
  for (int k0 = 0; k0 < K; k0 += 32) {
    __syncthreads();
    for (int i = 0; i < NLOAD; ++i)
      gl_lds16(gsrc[i] + k0, ldst[i]);
    __syncthreads();
    short8 af[4], bfr[NT];
    for (int mt = 0; mt < 4; ++mt) {
      int m = wm * 64 + mt * 16 + ln;
      int pos = quad ^ ((m >> 1) & 3);
      af[mt] = *(const short8*)&a_sh[m * 32 + pos * 8];
    }
    for (int nt = 0; nt < NT; ++nt) {
      int m = wn * (BN / 2) + nt * 16 + ln;
      int pos = quad ^ ((m >> 1) & 3);
      bfr[nt] = *(const short8*)&b_sh[m * 32 + pos * 8];
    }
    for (int mt = 0; mt < 4; ++mt)
      for (int nt = 0; nt < NT; ++nt)
        acc[mt][nt] = __builtin_amdgcn_mfma_f32_16x16x32_bf16(
            af[mt], bfr[nt], acc[mt][nt], 0, 0, 0);
  }
  for (int mt = 0; mt < 4; ++mt)
    for (int nt = 0; nt < NT; ++nt)
      for (int r = 0; r < 4; ++r) {
        long row = arow0 + wm * 64 + mt * 16 + quad * 4 + r;
        long col = brow0 + wn * (BN / 2) + nt * 16 + ln;
        float v = acc[mt][nt][r];
        if constexpr (OUT_BF16)
          ((unsigned short*)Cp)[row * N + col] = f2bf(v);
        else
          ((float*)Cp)[row * N + col] = v;
      }
}

// ---------------------------------------------------------------------------
// Kernel 2a: per-head RMSNorm + rotary for q,k. qhat/khat: [h][t][d] bf16.
// ---------------------------------------------------------------------------
__global__ __launch_bounds__(256) void qk_norm_rope(
    const unsigned short* __restrict__ qkv, unsigned short* __restrict__ qh,
    unsigned short* __restrict__ kh) {
  const int t = blockIdx.x;
  const int tid = threadIdx.x;
  const int h = tid >> 5, c = tid & 31;
  float cv[2], sv[2];
  for (int u = 0; u < 2; ++u) {
    int dd = 2 * c + u;
    if (dd < 32) {
      float ang = exp2f(-10.0f * (float)dd / 31.0f);  // (1/1024)^(dd/31)
      float th = (float)t * ang;
      sv[u] = __sinf(th); cv[u] = __cosf(th);
    } else { sv[u] = 0.f; cv[u] = 1.f; }
  }
  for (int which = 0; which < 2; ++which) {           // 0 = q, 1 = k
    const unsigned short* src = qkv + (long)t * 3072 + which * 1024 + h * 128;
    ushort2v aa = *(const ushort2v*)(src + 2 * c);
    ushort2v bb = *(const ushort2v*)(src + 64 + 2 * c);
    float x1[2] = { bf2f(aa[0]), bf2f(aa[1]) };
    float x2[2] = { bf2f(bb[0]), bf2f(bb[1]) };
    float ss = x1[0]*x1[0] + x1[1]*x1[1] + x2[0]*x2[0] + x2[1]*x2[1];
    for (int off = 1; off < 32; off <<= 1) ss += __shfl_xor(ss, off);
    float rn = rsqrtf(ss * (1.0f / 128.0f) + 1.1920929e-7f);
    ushort2v o1, o2;
    for (int u = 0; u < 2; ++u) {
      float y1 = ( x1[u] * cv[u] + x2[u] * sv[u]) * rn;
      float y2 = (-x1[u] * sv[u] + x2[u] * cv[u]) * rn;
      o1[u] = f2bf(y1); o2[u] = f2bf(y2);
    }
    unsigned short* dst = (which ? kh : qh) + ((long)h * T_SEQ + t) * 128;
    *(ushort2v*)(dst + 2 * c) = o1;
    *(ushort2v*)(dst + 64 + 2 * c) = o2;
  }
}

// ---------------------------------------------------------------------------
// Kernel 2b: v = l0*v + l1*ve, transpose to vt[h][d][t] bf16 via LDS.
// ---------------------------------------------------------------------------
__global__ __launch_bounds__(256) void v_combine_t(
    const unsigned short* __restrict__ qkv, const float* __restrict__ ve,
    const float* __restrict__ lambdas, unsigned short* __restrict__ vt) {
  __shared__ unsigned short lt[128 * 72];
  const int tt = blockIdx.x, h = blockIdx.y;
  const int tid = threadIdx.x;
  const float l0 = lambdas[0], l1 = lambdas[1];
  const int r = tid >> 2, cb = (tid & 3) * 32;
  const unsigned short* vs = qkv + (long)(tt * 64 + r) * 3072 + 2048 + h * 128 + cb;
  const float* es = ve + (long)(tt * 64 + r) * 1024 + h * 128 + cb;
  ushort8 vv[4];
  for (int q = 0; q < 4; ++q) vv[q] = *(const ushort8*)(vs + 8 * q);
  float4v ee[8];
  for (int q = 0; q < 8; ++q) ee[q] = *(const float4v*)(es + 4 * q);
  for (int j = 0; j < 32; ++j) {
    float v = bf2f(vv[j >> 3][j & 7]) * l0 + ee[j >> 2][j & 3] * l1;
    lt[(cb + j) * 72 + r] = f2bf(v);
  }
  __syncthreads();
  const int d = tid >> 1, half = (tid & 1) * 32;
  unsigned short* dst = vt + ((long)h * HD + d) * T_SEQ + tt * 64 + half;
  const unsigned short* srcl = &lt[d * 72 + half];
  *(ushort8*)(dst)      = *(const ushort8*)(srcl);
  *(ushort8*)(dst + 8)  = *(const ushort8*)(srcl + 8);
  *(ushort8*)(dst + 16) = *(const ushort8*)(srcl + 16);
  *(ushort8*)(dst + 24) = *(const ushort8*)(srcl + 24);
}

// ---------------------------------------------------------------------------
// Kernel 3a: chunked flash attention partials, transposed inner product.
// Grid (qt=32, h=8, ch=NCH); chunk covers kv-tiles [CHW*ch, min(+CHW-1, qt)].
// Per wave (16 q-rows): S^T = K*Q^T (mfma(kb, qf)) -> C rows=kv, cols=q=ln.
// Fixed-max softmax (|s|<=15.4): p = exp2(s*0.12*log2e - 16*log2e); l is a
// per-lane scalar. P^T B-frags for PV built by quad-shuffles of packed bf16.
// Y^T = V^T * P^T. Partials Yp bf16 [pidx][64 q][128 d], lp fp32 [pidx][64].
// K/V staged via VGPR prefetch (1 tile ahead), single LDS buffer.
// ---------------------------------------------------------------------------
#define ATT_C1 0.17312340490667562f   // 0.12 * log2(e)
#define ATT_C2 23.083120654223415f    // 16   * log2(e)

__global__ __launch_bounds__(256) void attn_part(
    const unsigned short* __restrict__ qh, const unsigned short* __restrict__ kh,
    const unsigned short* __restrict__ vt, unsigned short* __restrict__ Yp,
    float* __restrict__ lp) {
  __shared__ unsigned short k_sh[64 * 136];   // [kv][d]
  __shared__ unsigned short v_sh[128 * 72];   // [d][kv]
  const int tid = threadIdx.x;
  const int wave = tid >> 6, lane = tid & 63;
  const int ln = lane & 15, quad = lane >> 4;
  const int qt = blockIdx.x, h = blockIdx.y, ch = blockIdx.z;
  const int j0 = ch * CHW;
  if (j0 > qt) return;                        // uniform per block
  const int j1 = min(j0 + CHW - 1, qt);
  const int qrow0 = qt * 64 + wave * 16;
  const int qg = qrow0 + ln;                  // this lane's q row (cols of S^T)

  short8 qf[4];
  {
    const unsigned short* qbase = qh + ((long)h * T_SEQ + qg) * 128;
    for (int kc = 0; kc < 4; ++kc)
      qf[kc] = *(const short8*)(qbase + kc * 32 + quad * 8);
  }
  fx4 accy[8] = {};                           // Y^T: 8 d-tiles x (4 rows)
  float l_loc = 0.f;

  const int kr = tid >> 2, kcb = (tid & 3) * 32;   // K staging: 64 rows
  const int vr = tid >> 1, vhb = (tid & 1) * 32;   // V staging: 128 rows

  ushort8 kreg[4], vreg[4];
  {
    const unsigned short* src = kh + ((long)h * T_SEQ + j0 * 64 + kr) * 128 + kcb;
    for (int i = 0; i < 4; ++i) kreg[i] = *(const ushort8*)(src + 8 * i);
    const unsigned short* sv2 = vt + ((long)h * HD + vr) * T_SEQ + j0 * 64 + vhb;
    for (int i = 0; i < 4; ++i) vreg[i] = *(const ushort8*)(sv2 + 8 * i);
  }

  for (int jt = j0; jt <= j1; ++jt) {
    __syncthreads();                          // prior iter LDS reads done
    {
      unsigned short* d0 = &k_sh[kr * 136 + kcb];
      for (int i = 0; i < 4; ++i) *(ushort8*)(d0 + 8 * i) = kreg[i];
      unsigned short* d1 = &v_sh[vr * 72 + vhb];
      for (int i = 0; i < 4; ++i) *(ushort8*)(d1 + 8 * i) = vreg[i];
    }
    __syncthreads();
    {   // prefetch next tile (clamped; overlaps with compute below)
      int jn = (jt < j1) ? jt + 1 : jt;
      const unsigned short* src = kh + ((long)h * T_SEQ + jn * 64 + kr) * 128 + kcb;
      for (int i = 0; i < 4; ++i) kreg[i] = *(const ushort8*)(src + 8 * i);
      const unsigned short* sv2 = vt + ((long)h * HD + vr) * T_SEQ + jn * 64 + vhb;
      for (int i = 0; i < 4; ++i) vreg[i] = *(const ushort8*)(sv2 + 8 * i);
    }

    // S^T tiles: kt -> kv rows [kt*16, kt*16+16), cols q (=ln)
    fx4 s[4];
    for (int kt = 0; kt < 4; ++kt) {
      fx4 c = {0.f, 0.f, 0.f, 0.f};
      for (int kc = 0; kc < 4; ++kc) {
        short8 kb = *(const short8*)&k_sh[(kt * 16 + ln) * 136 + kc * 32 + quad * 8];
        c = __builtin_amdgcn_mfma_f32_16x16x32_bf16(kb, qf[kc], c, 0, 0, 0);
      }
      s[kt] = c;
    }
    const bool diag = (jt == qt);
    unsigned pk[4][2];                        // packed bf16 p, per kv-tile
    for (int kt = 0; kt < 4; ++kt) {
      float p[4];
      for (int r = 0; r < 4; ++r) {
        float pv = exp2f(fmaf(s[kt][r], ATT_C1, -ATT_C2));
        if (diag && (jt * 64 + kt * 16 + quad * 4 + r) > qg) pv = 0.f;
        p[r] = pv;
      }
      l_loc += (p[0] + p[1]) + (p[2] + p[3]);
      pk[kt][0] = f2bf2_t(p[0], p[1]);
      pk[kt][1] = f2bf2_t(p[2], p[3]);
    }
    // PV: Y^T += V^T * P^T.  B-frag (P^T) via quad shuffles:
    // kstep kc2: tile st=2*kc2+(quad>>1); srcA=((quad&1)*2)*16+ln, srcB=+16.
    const int laneA = ((quad & 1) << 5) + ln;
    for (int kc2 = 0; kc2 < 2; ++kc2) {
      unsigned d0a = __shfl((int)pk[2 * kc2][0],     laneA);
      unsigned d0b = __shfl((int)pk[2 * kc2 + 1][0], laneA);
      unsigned d1a = __shfl((int)pk[2 * kc2][1],     laneA);
      unsigned d1b = __shfl((int)pk[2 * kc2 + 1][1], laneA);
      unsigned d2a = __shfl((int)pk[2 * kc2][0],     laneA + 16);
      unsigned d2b = __shfl((int)pk[2 * kc2 + 1][0], laneA + 16);
      unsigned d3a = __shfl((int)pk[2 * kc2][1],     laneA + 16);
      unsigned d3b = __shfl((int)pk[2 * kc2 + 1][1], laneA + 16);
      union { unsigned u[4]; short8 s8; } bf;
      bf.u[0] = (quad & 2) ? d0b : d0a;
      bf.u[1] = (quad & 2) ? d1b : d1a;
      bf.u[2] = (quad & 2) ? d2b : d2a;
      bf.u[3] = (quad & 2) ? d3b : d3a;
      for (int dt = 0; dt < 8; ++dt) {
        short8 vb = *(const short8*)&v_sh[(dt * 16 + ln) * 72 + kc2 * 32 + quad * 8];
        accy[dt] = __builtin_amdgcn_mfma_f32_16x16x32_bf16(vb, bf.s8, accy[dt], 0, 0, 0);
      }
    }
  }

  // reduce l across quads (lanes ln, ln+16, ln+32, ln+48)
  l_loc += __shfl_xor(l_loc, 16);
  l_loc += __shfl_xor(l_loc, 32);
  const long pidx = (long)((h * 32 + qt) * NCH + ch);
  if (quad == 0) lp[pidx * 64 + wave * 16 + ln] = l_loc;
  unsigned short* yb = Yp + pidx * 8192 + (wave * 16 + ln) * 128;
  for (int dt = 0; dt < 8; ++dt) {
    ushort4v o;
    for (int r = 0; r < 4; ++r) o[r] = f2bf(accy[dt][r]);
    *(ushort4v*)(yb + dt * 16 + quad * 4) = o;
  }
}

// ---------------------------------------------------------------------------
// Kernel 3b: combine partials: Y = (sum_c Yp) / (sum_c lp) -> ybf [t][h*128+d].
// ---------------------------------------------------------------------------
__global__ __launch_bounds__(256) void attn_combine(
    const unsigned short* __restrict__ Yp, const float* __restrict__ lp,
    unsigned short* __restrict__ y) {
  const int qt = blockIdx.x, h = blockIdx.y;
  const int tid = threadIdx.x;
  const int row = tid >> 2, cb = (tid & 3) * 32;
  const int nc = qt / CHW + 1;
  float acc[32];
  for (int j = 0; j < 32; ++j) acc[j] = 0.f;
  float ltot = 0.f;
  for (int c = 0; c < nc; ++c) {
    long pidx = (long)((h * 32 + qt) * NCH + c);
    const unsigned short* ys = Yp + pidx * 8192 + row * 128 + cb;
    ltot += lp[pidx * 64 + row];
    for (int q8 = 0; q8 < 4; ++q8) {
      ushort8 v = *(const ushort8*)(ys + q8 * 8);
      for (int j = 0; j < 8; ++j) acc[q8 * 8 + j] += bf2f(v[j]);
    }
  }
  float inv = 1.f / ltot;
  unsigned short* dst = y + (long)(qt * 64 + row) * 1024 + h * 128 + cb;
  for (int q8 = 0; q8 < 4; ++q8) {
    ushort8 o;
    for (int j = 0; j < 8; ++j) o[j] = f2bf(acc[q8 * 8 + j] * inv);
    *(ushort8*)(dst + q8 * 8) = o;
  }
}

// ---------------------------------------------------------------------------
// Workspace layout (bytes), ~42 MB. Attention partials reuse dead regions:
//   0        : qkv_bf [2048][3072] bf16 (12MB) | attn: Yp bf16 (1280x16KB =
//   12582912 : x_bf   (4MB)                    |   20.97MB, spans 0..20.97M)
//   16777216 : wqkv   (6MB)                    | attn: lp fp32 @20971520
//   23068672 : wproj  (2MB, live until GEMM2)
//   25165824 : qhat [8][2048][128] (4MB)
//   29360128 : khat (4MB)
//   33554432 : vt   [8][128][2048] (4MB)
//   37748736 : ybf  [2048][1024] (4MB)
// ---------------------------------------------------------------------------
extern "C" void kernel_launch(void* const* d_in, const int* in_sizes, int n_in,
                              void* d_out, int out_size, void* d_ws, size_t ws_size,
                              hipStream_t stream) {
  const float* x       = (const float*)d_in[0];
  const float* ve      = (const float*)d_in[1];
  const float* qkv_w   = (const float*)d_in[2];
  const float* lambdas = (const float*)d_in[3];
  const float* c_proj  = (const float*)d_in[4];
  char* ws = (char*)d_ws;
  unsigned short* qkv_bf = (unsigned short*)(ws);
  unsigned short* x_bf   = (unsigned short*)(ws + 12582912);
  unsigned short* wqkv   = (unsigned short*)(ws + 16777216);
  unsigned short* wproj  = (unsigned short*)(ws + 23068672);
  unsigned short* qhat   = (unsigned short*)(ws + 25165824);
  unsigned short* khat   = (unsigned short*)(ws + 29360128);
  unsigned short* vtb    = (unsigned short*)(ws + 33554432);
  unsigned short* ybf    = (unsigned short*)(ws + 37748736);
  unsigned short* Yp     = (unsigned short*)(ws);              // reuse, 21MB
  float*          lpart  = (float*)(ws + 20971520);            // reuse, 328KB
  float* out = (float*)d_out;

  cast3_kernel<<<6144, 256, 0, stream>>>(x, qkv_w, c_proj, x_bf);
  gemm_bt2<true, 128><<<dim3(24, 16), 256, 0, stream>>>(x_bf, wqkv, qkv_bf, 2048, 3072, 1024);
  qk_norm_rope<<<2048, 256, 0, stream>>>(qkv_bf, qhat, khat);
  v_combine_t<<<dim3(32, 8), 256, 0, stream>>>(qkv_bf, ve, lambdas, vtb);
  attn_part<<<dim3(32, 8, NCH), 256, 0, stream>>>(qhat, khat, vtb, Yp, lpart);
  attn_combine<<<dim3(32, 8), 256, 0, stream>>>(Yp, lpart, ybf);
  gemm_bt2<false, 64><<<dim3(16, 16), 256, 0, stream>>>(ybf, wproj, out, 2048, 1024, 1024);
}